// Round 1
// baseline (678.906 us; speedup 1.0000x reference)
//
#include <hip/hip_runtime.h>
#include <math.h>

// TensorSketch (degree-3 polynomial count sketch) for B=8192, F=4096, N=512.
// out[b] = irfft( prod_d rfft(countsketch_d(X[b])) )  ==  s0 (*) s1 (*) s2 (circular conv)
// Strategy: 1 block = 8 rows = 4 row-pairs. Pack pair rows as real/imag of one
// complex sequence -> full complex FFT-512 handles two rows at once.
// Forward: radix-2 DIF (natural in, bit-rev out). Product done in bit-rev order
// with partner index rev9((512 - rev9(j)) & 511). Inverse: radix-2 DIT
// (bit-rev in, natural out). Scale 1/512 at store.

#define F_DIM 4096
#define NC 512
#define DEG 3
#define ROWS_PER_BLK 8
#define PAIRS 4
#define THREADS 256

__device__ __forceinline__ float2 cmul(float2 a, float2 b) {
    return make_float2(a.x * b.x - a.y * b.y, a.x * b.y + a.y * b.x);
}

__global__ __launch_bounds__(THREADS, 2) void ts_kernel(
    const float* __restrict__ X,
    const int* __restrict__ idxh,
    const int* __restrict__ bith,
    float* __restrict__ out)
{
    __shared__ float2 sk[PAIRS][DEG][NC];   // 48 KB: pair-packed sketches / spectra
    __shared__ float2 tw[NC / 2];           // 2 KB:  tw[t] = exp(-2*pi*i*t/512)

    const int tid  = threadIdx.x;
    const int lane = tid & 63;
    const int wave = tid >> 6;
    const int row0 = blockIdx.x * ROWS_PER_BLK;

    // --- twiddle table (once per block) ---
    if (tid < NC / 2) {
        float ang = -2.0f * 3.14159265358979323846f * (float)tid / (float)NC;
        float s, c;
        __sincosf(ang, &s, &c);
        tw[tid] = make_float2(c, s);
    }

    // --- zero sketches ---
    for (int i = tid; i < PAIRS * DEG * NC; i += THREADS)
        ((float2*)sk)[i] = make_float2(0.0f, 0.0f);
    __syncthreads();

    // --- count-sketch scatter: X read once, 3 degrees x 8 rows per element ---
    for (int c = 0; c < F_DIM; c += THREADS) {
        const int f = c + tid;
        float xv[ROWS_PER_BLK];
        #pragma unroll
        for (int r = 0; r < ROWS_PER_BLK; ++r)
            xv[r] = X[(size_t)(row0 + r) * F_DIM + f];
        #pragma unroll
        for (int d = 0; d < DEG; ++d) {
            const int bucket = idxh[d * F_DIM + f];
            const float sg = (float)(2 * bith[d * F_DIM + f] - 1);
            #pragma unroll
            for (int r = 0; r < ROWS_PER_BLK; ++r) {
                float* cell = (float*)&sk[r >> 1][d][bucket] + (r & 1);
                atomicAdd(cell, xv[r] * sg);
            }
        }
    }
    __syncthreads();

    // --- forward FFTs: radix-2 DIF, wave `w` owns pair `w`, 3 arrays ---
    for (int s = 0; s < 9; ++s) {
        const int h = 256 >> s;               // half-size of current transform
        #pragma unroll
        for (int d = 0; d < DEG; ++d) {
            float2* z = sk[wave][d];
            #pragma unroll
            for (int it = 0; it < 4; ++it) {
                const int u  = lane + (it << 6);      // 0..255 butterfly id
                const int j  = u & (h - 1);
                const int g  = u >> (8 - s);
                const int i1 = (g << (9 - s)) + j;
                const int i2 = i1 + h;
                float2 a = z[i1], b = z[i2];
                float2 t = make_float2(a.x - b.x, a.y - b.y);
                z[i1] = make_float2(a.x + b.x, a.y + b.y);
                z[i2] = cmul(t, tw[j << s]);
            }
        }
        __syncthreads();
    }

    // --- extraction + spectral product (bit-reversed domain), regs only ---
    // z = a + i*b (a=row0 sketch, b=row1).  A = (Z[k]+conj(Z[N-k]))/2,
    // B = -i*(Z[k]-conj(Z[N-k]))/2.  P0 = prod A_d, P1 = prod B_d.
    float2 P0[8], P1[8];
    #pragma unroll
    for (int it = 0; it < 8; ++it) {
        const int j  = lane + (it << 6);
        const int k  = (int)(__brev((unsigned)j) >> 23);
        const int kp = (NC - k) & (NC - 1);
        const int jp = (int)(__brev((unsigned)kp) >> 23);
        float2 p0 = make_float2(1.0f, 0.0f);
        float2 p1 = make_float2(1.0f, 0.0f);
        #pragma unroll
        for (int d = 0; d < DEG; ++d) {
            float2 zk = sk[wave][d][j];
            float2 zp = sk[wave][d][jp];
            float2 A  = make_float2(0.5f * (zk.x + zp.x), 0.5f * (zk.y - zp.y));
            float2 Bv = make_float2(0.5f * (zk.y + zp.y), 0.5f * (zp.x - zk.x));
            p0 = cmul(p0, A);
            p1 = cmul(p1, Bv);
        }
        P0[it] = p0;
        P1[it] = p1;
    }
    __syncthreads();   // all extraction reads done before overwriting sk[w][0]

    // Q = P0 + i*P1  (still bit-reversed order) -> sk[wave][0]
    #pragma unroll
    for (int it = 0; it < 8; ++it) {
        const int j = lane + (it << 6);
        sk[wave][0][j] = make_float2(P0[it].x - P1[it].y, P0[it].y + P1[it].x);
    }
    __syncthreads();

    // --- inverse FFT: radix-2 DIT (bit-rev in, natural out) ---
    for (int s = 0; s < 9; ++s) {
        const int h = 1 << s;
        float2* z = sk[wave][0];
        #pragma unroll
        for (int it = 0; it < 4; ++it) {
            const int u  = lane + (it << 6);
            const int j  = u & (h - 1);
            const int g  = u >> s;
            const int i1 = (g << (s + 1)) + j;
            const int i2 = i1 + h;
            float2 a = z[i1];
            float2 w = tw[j << (8 - s)];
            w.y = -w.y;                        // conj -> inverse twiddle
            float2 b = cmul(z[i2], w);
            z[i1] = make_float2(a.x + b.x, a.y + b.y);
            z[i2] = make_float2(a.x - b.x, a.y - b.y);
        }
        __syncthreads();
    }

    // --- store: q = p0 + i*p1 (both real), scale by 1/512 ---
    const float scale = 1.0f / (float)NC;
    const int r0 = row0 + wave * 2;
    #pragma unroll
    for (int it = 0; it < 8; ++it) {
        const int n = lane + (it << 6);
        const float2 q = sk[wave][0][n];
        out[(size_t)r0 * NC + n]       = q.x * scale;
        out[(size_t)(r0 + 1) * NC + n] = q.y * scale;
    }
}

extern "C" void kernel_launch(void* const* d_in, const int* in_sizes, int n_in,
                              void* d_out, int out_size, void* d_ws, size_t ws_size,
                              hipStream_t stream) {
    const float* X    = (const float*)d_in[0];
    const int*   idxh = (const int*)d_in[1];
    const int*   bith = (const int*)d_in[2];
    float*       outp = (float*)d_out;

    const int n_rows = in_sizes[0] / F_DIM;          // 8192
    const int blocks = n_rows / ROWS_PER_BLK;        // 1024
    ts_kernel<<<blocks, THREADS, 0, stream>>>(X, idxh, bith, outp);
}

// Round 2
// 672.357 us; speedup vs baseline: 1.0097x; 1.0097x over previous
//
#include <hip/hip_runtime.h>
#include <math.h>

// TensorSketch degree-3: out[b] = irfft( prod_d rfft(countsketch_d(X[b])) )
// B=8192, F=4096, N=512. Wave-independent design: each 64-lane wave owns one
// row PAIR (rows packed as real/imag of one complex FFT-512) through ALL
// phases: scatter -> 3x fwd FFT -> spectral product -> inv FFT -> store.
// ZERO __syncthreads. LDS atomics via unsafeAtomicAdd -> native ds_add_f32.

#define F_DIM 4096
#define NC 512
#define DEG 3
#define PAIRS 4            // pairs per block (1 per wave)
#define THREADS 256        // 4 waves
#define PI_F 3.14159265358979323846f

__device__ __forceinline__ float2 cmul(float2 a, float2 b) {
    return make_float2(a.x * b.x - a.y * b.y, a.x * b.y + a.y * b.x);
}

__global__ __launch_bounds__(THREADS, 2) void ts_kernel(
    const float* __restrict__ X,
    const int* __restrict__ idxh,
    const int* __restrict__ bith,
    float* __restrict__ out)
{
    __shared__ float2 sk[PAIRS][DEG][NC];   // 48 KB
    __shared__ float2 tw[NC / 2];           // 2 KB shared twiddles

    const int tid  = threadIdx.x;
    const int lane = tid & 63;
    const int wave = tid >> 6;
    const int r0   = blockIdx.x * (2 * PAIRS) + wave * 2;   // this wave's rows

    // Every wave writes the FULL twiddle table (identical values, so concurrent
    // redundant writes are benign and no barrier is needed before use).
    #pragma unroll
    for (int t = lane; t < NC / 2; t += 64) {
        float sv, cv;
        __sincosf(-2.0f * PI_F * (float)t / (float)NC, &sv, &cv);
        tw[t] = make_float2(cv, sv);
    }

    // Zero this wave's own sketches (wave-private; in-wave ordering suffices).
    #pragma unroll
    for (int d = 0; d < DEG; ++d)
        for (int i = lane; i < NC; i += 64)
            sk[wave][d][i] = make_float2(0.0f, 0.0f);

    // ---- count-sketch scatter: this wave's 2 rows only, float4-vectorized ----
    const float4* X0 = (const float4*)(X + (size_t)r0 * F_DIM);
    const float4* X1 = (const float4*)(X + (size_t)(r0 + 1) * F_DIM);
    for (int c = 0; c < F_DIM / 4; c += 64) {
        const int q = c + lane;                 // float4 index into the row
        const float4 a = X0[q];
        const float4 b = X1[q];
        #pragma unroll
        for (int d = 0; d < DEG; ++d) {
            const int4 iv = ((const int4*)(idxh + d * F_DIM))[q];
            const int4 bv = ((const int4*)(bith + d * F_DIM))[q];
            #define SCAT(C) { \
                const int   bu = iv.C; \
                const float sg = (float)(2 * bv.C - 1); \
                unsafeAtomicAdd(&sk[wave][d][bu].x, a.C * sg); \
                unsafeAtomicAdd(&sk[wave][d][bu].y, b.C * sg); }
            SCAT(x) SCAT(y) SCAT(z) SCAT(w)
            #undef SCAT
        }
    }
    // No barrier: everything below touches only sk[wave][*] (self-written).

    // ---- forward FFTs: radix-2 DIF (natural in -> bit-rev out), 3 arrays ----
    for (int s = 0; s < 9; ++s) {
        const int h = 256 >> s;
        #pragma unroll
        for (int d = 0; d < DEG; ++d) {
            float2* z = sk[wave][d];
            #pragma unroll
            for (int it = 0; it < 4; ++it) {
                const int u  = lane + (it << 6);
                const int j  = u & (h - 1);
                const int g  = u >> (8 - s);
                const int i1 = (g << (9 - s)) + j;
                const int i2 = i1 + h;
                float2 a = z[i1], b = z[i2];
                float2 t = make_float2(a.x - b.x, a.y - b.y);
                z[i1] = make_float2(a.x + b.x, a.y + b.y);
                z[i2] = cmul(t, tw[j << s]);
            }
        }
    }

    // ---- extraction + spectral product (bit-reversed domain) ----
    // z = a + i*b; A=(Z[k]+conj(Z[N-k]))/2; B=-i*(Z[k]-conj(Z[N-k]))/2
    float2 P0[8], P1[8];
    #pragma unroll
    for (int it = 0; it < 8; ++it) {
        const int j  = lane + (it << 6);
        const int k  = (int)(__brev((unsigned)j) >> 23);
        const int kp = (NC - k) & (NC - 1);
        const int jp = (int)(__brev((unsigned)kp) >> 23);
        float2 p0 = make_float2(1.0f, 0.0f);
        float2 p1 = make_float2(1.0f, 0.0f);
        #pragma unroll
        for (int d = 0; d < DEG; ++d) {
            float2 zk = sk[wave][d][j];
            float2 zp = sk[wave][d][jp];
            float2 A  = make_float2(0.5f * (zk.x + zp.x), 0.5f * (zk.y - zp.y));
            float2 Bv = make_float2(0.5f * (zk.y + zp.y), 0.5f * (zp.x - zk.x));
            p0 = cmul(p0, A);
            p1 = cmul(p1, Bv);
        }
        P0[it] = p0;
        P1[it] = p1;
    }
    // Wave executes in lockstep: all reads above retire before writes below
    // (program order within one wave) -> no barrier needed.
    #pragma unroll
    for (int it = 0; it < 8; ++it) {
        const int j = lane + (it << 6);
        sk[wave][0][j] = make_float2(P0[it].x - P1[it].y, P0[it].y + P1[it].x);
    }

    // ---- inverse FFT: radix-2 DIT (bit-rev in -> natural out) ----
    for (int s = 0; s < 9; ++s) {
        const int h = 1 << s;
        float2* z = sk[wave][0];
        #pragma unroll
        for (int it = 0; it < 4; ++it) {
            const int u  = lane + (it << 6);
            const int j  = u & (h - 1);
            const int g  = u >> s;
            const int i1 = (g << (s + 1)) + j;
            const int i2 = i1 + h;
            float2 a = z[i1];
            float2 w = tw[j << (8 - s)];
            w.y = -w.y;                        // conj -> inverse twiddle
            float2 b = cmul(z[i2], w);
            z[i1] = make_float2(a.x + b.x, a.y + b.y);
            z[i2] = make_float2(a.x - b.x, a.y - b.y);
        }
    }

    // ---- store: Re -> row r0, Im -> row r0+1, scale 1/512, coalesced ----
    const float scale = 1.0f / (float)NC;
    #pragma unroll
    for (int it = 0; it < 8; ++it) {
        const int n = lane + (it << 6);
        const float2 q = sk[wave][0][n];
        out[(size_t)r0 * NC + n]       = q.x * scale;
        out[(size_t)(r0 + 1) * NC + n] = q.y * scale;
    }
}

extern "C" void kernel_launch(void* const* d_in, const int* in_sizes, int n_in,
                              void* d_out, int out_size, void* d_ws, size_t ws_size,
                              hipStream_t stream) {
    const float* X    = (const float*)d_in[0];
    const int*   idxh = (const int*)d_in[1];
    const int*   bith = (const int*)d_in[2];
    float*       outp = (float*)d_out;

    const int n_rows = in_sizes[0] / F_DIM;            // 8192
    const int blocks = n_rows / (2 * PAIRS);           // 1024
    ts_kernel<<<blocks, THREADS, 0, stream>>>(X, idxh, bith, outp);
}

// Round 4
// 267.576 us; speedup vs baseline: 2.5372x; 2.5128x over previous
//
#include <hip/hip_runtime.h>
#include <math.h>

// TensorSketch degree-3: out[b] = irfft( prod_d rfft(countsketch_d(X[b])) )
// B=8192, F=4096, N=512.
//
// The count-sketch hash is FIXED across rows -> it is a constant sparse
// matrix. Kernel 1 (build_csr) inverts it into CSR form in d_ws: per degree,
// entries sorted by bucket (ushort: feature | bit<<15) + offsets.
// Kernel 2 gathers (NO atomics): stage row-pair X in LDS, each thread sums its
// buckets' feature lists, then per-wave FFT-512 (pair packed as real/imag),
// spectral product, inverse FFT, store. LDS = 48 KB sk + 32 KB xstage = 80 KB
// -> 2 blocks/CU. Twiddle table aliases the dead xstage during FFT phases.
//
// R4 fix vs R3: sign decode was inverted (bit=1 means +1, per sgn = 2*bit-1).
// R3 produced exactly -ref (absmax = 2*max|ref|).

#define F_DIM 4096
#define NC 512
#define DEG 3
#define THREADS 256
#define PI_F 3.14159265358979323846f

#define OFS_STRIDE 520            // ushorts per degree in the offsets table
#define ENT_BYTE_OFF 4096         // entries start at ws + 4 KB

__device__ __forceinline__ float2 cmul(float2 a, float2 b) {
    return make_float2(a.x * b.x - a.y * b.y, a.x * b.y + a.y * b.x);
}

// ---------------- kernel 1: build CSR (bucket -> (feature,bit) list) ----------------
__global__ __launch_bounds__(512) void build_csr(
    const int* __restrict__ idxh,
    const int* __restrict__ bith,
    ushort* __restrict__ ofs_g,    // [DEG][OFS_STRIDE]
    ushort* __restrict__ ent_g)    // [DEG][F_DIM]
{
    __shared__ unsigned cnt[NC];
    __shared__ unsigned scn[NC];
    const int d = blockIdx.x;
    const int t = threadIdx.x;

    if (t < NC) cnt[t] = 0;
    __syncthreads();
    for (int f = t; f < F_DIM; f += 512)
        atomicAdd(&cnt[idxh[d * F_DIM + f]], 1u);
    __syncthreads();

    // inclusive scan of cnt into scn (Hillis-Steele, 512 bins)
    if (t < NC) scn[t] = cnt[t];
    __syncthreads();
    for (int off = 1; off < NC; off <<= 1) {
        unsigned v = 0;
        if (t < NC) { v = scn[t]; if (t >= off) v += scn[t - off]; }
        __syncthreads();
        if (t < NC) scn[t] = v;
        __syncthreads();
    }

    // exclusive offsets + reset cursors
    if (t < NC) {
        const unsigned excl = t ? scn[t - 1] : 0u;
        ofs_g[d * OFS_STRIDE + t] = (ushort)excl;
        cnt[t] = excl;                       // reuse as placement cursor
    }
    if (t == 0) ofs_g[d * OFS_STRIDE + NC] = (ushort)F_DIM;
    __syncthreads();

    // placement
    for (int f = t; f < F_DIM; f += 512) {
        const int b = idxh[d * F_DIM + f];
        const unsigned pos = atomicAdd(&cnt[b], 1u);
        ent_g[d * F_DIM + pos] = (ushort)(f | (bith[d * F_DIM + f] << 15));
    }
}

// ---------------- kernel 2: gather + FFT + product + inverse + store ----------------
__global__ __launch_bounds__(THREADS, 2) void ts_kernel(
    const float* __restrict__ X,
    const ushort* __restrict__ ofs_g,
    const ushort* __restrict__ ent_g,
    float* __restrict__ out)
{
    __shared__ float2 sk[4][DEG][NC];   // 48 KB: 4 pairs x 3 sketches
    __shared__ float2 xst[F_DIM];       // 32 KB: one pair's X, {row0,row1} packed
    float2* tw = xst;                   // twiddles alias xst once staging is dead

    const int tid  = threadIdx.x;
    const int lane = tid & 63;
    const int wave = tid >> 6;

    // This thread's 6 gather jobs: (d, bucket) with bucket in {tid, tid+256}.
    // Offsets are L2-hot and identical for all pairs -> hoist into registers.
    int je0[DEG][2], je1[DEG][2];
    #pragma unroll
    for (int d = 0; d < DEG; ++d)
        #pragma unroll
        for (int h = 0; h < 2; ++h) {
            const int b = tid + (h << 8);
            je0[d][h] = ofs_g[d * OFS_STRIDE + b];
            je1[d][h] = ofs_g[d * OFS_STRIDE + b + 1];
        }

    // ---- per-pair: stage X then gather all 3 sketches (atomic-free) ----
    for (int p = 0; p < 4; ++p) {
        const int r0 = blockIdx.x * 8 + p * 2;
        const float* X0 = X + (size_t)r0 * F_DIM;
        const float* X1 = X0 + F_DIM;
        #pragma unroll 4
        for (int i = tid; i < F_DIM; i += THREADS)
            xst[i] = make_float2(X0[i], X1[i]);   // coalesced; even-bank 2-way (free)
        __syncthreads();

        #pragma unroll
        for (int d = 0; d < DEG; ++d)
            #pragma unroll
            for (int h = 0; h < 2; ++h) {
                const int b = tid + (h << 8);
                const ushort* ep = ent_g + d * F_DIM;
                float ax = 0.0f, ay = 0.0f;
                int e = je0[d][h];
                const int eend = je1[d][h];
                // chunk x4: issue 4 independent entry loads before use
                // sign: bit=1 -> +1, bit=0 -> -1 (sgn = 2*bit - 1)
                for (; e + 4 <= eend; e += 4) {
                    const ushort u0 = ep[e], u1 = ep[e + 1], u2 = ep[e + 2], u3 = ep[e + 3];
                    const float2 v0 = xst[u0 & 4095], v1 = xst[u1 & 4095];
                    const float2 v2 = xst[u2 & 4095], v3 = xst[u3 & 4095];
                    const float s0 = (u0 & 0x8000) ? 1.0f : -1.0f;
                    const float s1 = (u1 & 0x8000) ? 1.0f : -1.0f;
                    const float s2 = (u2 & 0x8000) ? 1.0f : -1.0f;
                    const float s3 = (u3 & 0x8000) ? 1.0f : -1.0f;
                    ax += s0 * v0.x + s1 * v1.x + s2 * v2.x + s3 * v3.x;
                    ay += s0 * v0.y + s1 * v1.y + s2 * v2.y + s3 * v3.y;
                }
                for (; e < eend; ++e) {
                    const ushort u = ep[e];
                    const float2 v = xst[u & 4095];
                    const float s = (u & 0x8000) ? 1.0f : -1.0f;
                    ax += s * v.x; ay += s * v.y;
                }
                sk[p][d][b] = make_float2(ax, ay);   // b=tid(+256): coalesced, conflict-free
            }
        __syncthreads();   // sk[p] complete; xst free for next pair
    }

    // ---- twiddles into dead xst area (every wave writes the full table;
    //      identical values -> concurrent redundant writes are benign) ----
    #pragma unroll
    for (int t = lane; t < NC / 2; t += 64) {
        float sv, cv;
        __sincosf(-2.0f * PI_F * (float)t / (float)NC, &sv, &cv);
        tw[t] = make_float2(cv, sv);
    }

    // ---- forward FFTs: radix-2 DIF (natural -> bit-rev), wave-private ----
    for (int s = 0; s < 9; ++s) {
        const int h = 256 >> s;
        #pragma unroll
        for (int d = 0; d < DEG; ++d) {
            float2* z = sk[wave][d];
            #pragma unroll
            for (int it = 0; it < 4; ++it) {
                const int u  = lane + (it << 6);
                const int j  = u & (h - 1);
                const int g  = u >> (8 - s);
                const int i1 = (g << (9 - s)) + j;
                const int i2 = i1 + h;
                float2 a = z[i1], b = z[i2];
                float2 t = make_float2(a.x - b.x, a.y - b.y);
                z[i1] = make_float2(a.x + b.x, a.y + b.y);
                z[i2] = cmul(t, tw[j << s]);
            }
        }
    }

    // ---- extraction + spectral product (bit-reversed domain) ----
    // z = a + i*b; A=(Z[k]+conj(Z[N-k]))/2; B=-i*(Z[k]-conj(Z[N-k]))/2
    float2 P0[8], P1[8];
    #pragma unroll
    for (int it = 0; it < 8; ++it) {
        const int j  = lane + (it << 6);
        const int k  = (int)(__brev((unsigned)j) >> 23);
        const int kp = (NC - k) & (NC - 1);
        const int jp = (int)(__brev((unsigned)kp) >> 23);
        float2 p0 = make_float2(1.0f, 0.0f);
        float2 p1 = make_float2(1.0f, 0.0f);
        #pragma unroll
        for (int d = 0; d < DEG; ++d) {
            float2 zk = sk[wave][d][j];
            float2 zp = sk[wave][d][jp];
            float2 A  = make_float2(0.5f * (zk.x + zp.x), 0.5f * (zk.y - zp.y));
            float2 Bv = make_float2(0.5f * (zk.y + zp.y), 0.5f * (zp.x - zk.x));
            p0 = cmul(p0, A);
            p1 = cmul(p1, Bv);
        }
        P0[it] = p0;
        P1[it] = p1;
    }
    #pragma unroll
    for (int it = 0; it < 8; ++it) {
        const int j = lane + (it << 6);
        sk[wave][0][j] = make_float2(P0[it].x - P1[it].y, P0[it].y + P1[it].x);
    }

    // ---- inverse FFT: radix-2 DIT (bit-rev -> natural) ----
    for (int s = 0; s < 9; ++s) {
        const int h = 1 << s;
        float2* z = sk[wave][0];
        #pragma unroll
        for (int it = 0; it < 4; ++it) {
            const int u  = lane + (it << 6);
            const int j  = u & (h - 1);
            const int g  = u >> s;
            const int i1 = (g << (s + 1)) + j;
            const int i2 = i1 + h;
            float2 a = z[i1];
            float2 w = tw[j << (8 - s)];
            w.y = -w.y;
            float2 b = cmul(z[i2], w);
            z[i1] = make_float2(a.x + b.x, a.y + b.y);
            z[i2] = make_float2(a.x - b.x, a.y - b.y);
        }
    }

    // ---- store: Re -> row r0, Im -> row r0+1, scale 1/512 ----
    const float scale = 1.0f / (float)NC;
    const int r0 = blockIdx.x * 8 + wave * 2;
    #pragma unroll
    for (int it = 0; it < 8; ++it) {
        const int n = lane + (it << 6);
        const float2 q = sk[wave][0][n];
        out[(size_t)r0 * NC + n]       = q.x * scale;
        out[(size_t)(r0 + 1) * NC + n] = q.y * scale;
    }
}

extern "C" void kernel_launch(void* const* d_in, const int* in_sizes, int n_in,
                              void* d_out, int out_size, void* d_ws, size_t ws_size,
                              hipStream_t stream) {
    const float* X    = (const float*)d_in[0];
    const int*   idxh = (const int*)d_in[1];
    const int*   bith = (const int*)d_in[2];
    float*       outp = (float*)d_out;

    ushort* ofs_g = (ushort*)d_ws;                              // 3*520*2 B < 4 KB
    ushort* ent_g = (ushort*)((char*)d_ws + ENT_BYTE_OFF);      // 3*4096*2 B = 24 KB

    build_csr<<<DEG, 512, 0, stream>>>(idxh, bith, ofs_g, ent_g);

    const int n_rows = in_sizes[0] / F_DIM;            // 8192
    const int blocks = n_rows / 8;                     // 1024 (4 pairs per block)
    ts_kernel<<<blocks, THREADS, 0, stream>>>(X, ofs_g, ent_g, outp);
}

// Round 5
// 263.244 us; speedup vs baseline: 2.5790x; 1.0165x over previous
//
#include <hip/hip_runtime.h>
#include <math.h>

// TensorSketch degree-3: out[b] = irfft( prod_d rfft(countsketch_d(X[b])) )
// B=8192, F=4096, N=512.
//
// R5: fully register-resident FFT. Wave owns a row-pair packed as one complex
// sequence, 8 float2 regs/lane (position n = it*64 + lane). DIF fwd: stages on
// register bits (it) are pure VALU; stages on lane bits are __shfl_xor. All
// twiddles hoisted to 13 float2 regs (reused x3 fwd + conj for inverse).
// Conjugate-partner in bit-rev domain: jp = u XOR (2^msb(u)-1)  ==
// shfl_xor(z[sigma(it)], 63) for it>=1 (sigma: 1->1, 2<->3, 4<->7, 5<->6),
// general shfl for it==0. LDS only for X staging (32 KB) + gather handoff
// exchange (12 KB) = 44 KB -> 3 blocks/CU. Gather is CSR-driven (no atomics),
// built once per launch by build_csr.

#define F_DIM 4096
#define NC 512
#define DEG 3
#define THREADS 256
#define PI_F 3.14159265358979323846f

#define OFS_STRIDE 520            // ushorts per degree in the offsets table
#define ENT_BYTE_OFF 4096         // entries start at ws + 4 KB

__device__ __forceinline__ float2 cmul(float2 a, float2 b) {
    return make_float2(a.x * b.x - a.y * b.y, a.x * b.y + a.y * b.x);
}
__device__ __forceinline__ float2 cmulc(float2 a, float2 b) {   // a * conj(b)
    return make_float2(a.x * b.x + a.y * b.y, a.y * b.x - a.x * b.y);
}
__device__ __forceinline__ float2 shflx(float2 v, int m) {
    return make_float2(__shfl_xor(v.x, m), __shfl_xor(v.y, m));
}

// DIF lane-stage: lower: a+b ; upper: (a-b)*w  (own value is b for upper lane)
__device__ __forceinline__ void fwd_lane_stage(float2 (&s)[8], int lane, int m, float2 w) {
    const bool up = (lane & m) != 0;
    const float sg = up ? -1.0f : 1.0f;
    const float2 weff = up ? w : make_float2(1.0f, 0.0f);
    #pragma unroll
    for (int r = 0; r < 8; ++r) {
        const float2 zz = s[r];
        const float2 pp = shflx(zz, m);
        const float2 dd = make_float2(fmaf(sg, zz.x, pp.x), fmaf(sg, zz.y, pp.y));
        s[r] = cmul(dd, weff);
    }
}
// DIT lane-stage: t = b*conj(w); lower: a+t ; upper: a-t
__device__ __forceinline__ void inv_lane_stage(float2 (&s)[8], int lane, int m, float2 w) {
    const bool up = (lane & m) != 0;
    const float sg = up ? -1.0f : 1.0f;
    #pragma unroll
    for (int r = 0; r < 8; ++r) {
        const float2 zz = s[r];
        const float2 pp = shflx(zz, m);
        const float2 a  = up ? pp : zz;
        const float2 bs = up ? zz : pp;
        const float2 t  = cmulc(bs, w);
        s[r] = make_float2(fmaf(sg, t.x, a.x), fmaf(sg, t.y, a.y));
    }
}

// ---------------- kernel 1: build CSR (bucket -> (feature,bit) list) ----------------
__global__ __launch_bounds__(512) void build_csr(
    const int* __restrict__ idxh,
    const int* __restrict__ bith,
    ushort* __restrict__ ofs_g,    // [DEG][OFS_STRIDE]
    ushort* __restrict__ ent_g)    // [DEG][F_DIM]
{
    __shared__ unsigned cnt[NC];
    __shared__ unsigned scn[NC];
    const int d = blockIdx.x;
    const int t = threadIdx.x;

    if (t < NC) cnt[t] = 0;
    __syncthreads();
    for (int f = t; f < F_DIM; f += 512)
        atomicAdd(&cnt[idxh[d * F_DIM + f]], 1u);
    __syncthreads();

    if (t < NC) scn[t] = cnt[t];
    __syncthreads();
    for (int off = 1; off < NC; off <<= 1) {
        unsigned v = 0;
        if (t < NC) { v = scn[t]; if (t >= off) v += scn[t - off]; }
        __syncthreads();
        if (t < NC) scn[t] = v;
        __syncthreads();
    }

    if (t < NC) {
        const unsigned excl = t ? scn[t - 1] : 0u;
        ofs_g[d * OFS_STRIDE + t] = (ushort)excl;
        cnt[t] = excl;                       // reuse as placement cursor
    }
    if (t == 0) ofs_g[d * OFS_STRIDE + NC] = (ushort)F_DIM;
    __syncthreads();

    for (int f = t; f < F_DIM; f += 512) {
        const int b = idxh[d * F_DIM + f];
        const unsigned pos = atomicAdd(&cnt[b], 1u);
        ent_g[d * F_DIM + pos] = (ushort)(f | (bith[d * F_DIM + f] << 15));
    }
}

// ---------------- kernel 2: gather + register FFT + product + inverse + store ----------------
__global__ __launch_bounds__(THREADS, 3) void ts_kernel(
    const float* __restrict__ X,
    const ushort* __restrict__ ofs_g,
    const ushort* __restrict__ ent_g,
    float* __restrict__ out)
{
    __shared__ float4 xst4[F_DIM / 2];    // 32 KB: one pair's X, {r0,r1} packed float2
    __shared__ float2 exch[DEG][NC];      // 12 KB: gather -> wave handoff
    float2* xst = (float2*)xst4;

    const int tid  = threadIdx.x;
    const int lane = tid & 63;
    const int wave = tid >> 6;

    // ---- hoist CSR offsets (L2-hot, same for all pairs) ----
    int je0[DEG][2], je1[DEG][2];
    #pragma unroll
    for (int d = 0; d < DEG; ++d)
        #pragma unroll
        for (int h = 0; h < 2; ++h) {
            const int b = tid + (h << 8);
            je0[d][h] = ofs_g[d * OFS_STRIDE + b];
            je1[d][h] = ofs_g[d * OFS_STRIDE + b + 1];
        }

    // ---- hoist twiddles: W = exp(-2*pi*i/512) powers, per (stage, it, lane) ----
    const float wang = -2.0f * PI_F / 512.0f;
    float2 tw0[4], tw1[2], tw2, tw3, tw4, tw5, tw6, tw7;
    #pragma unroll
    for (int c = 0; c < 4; ++c) {
        float sv, cv; __sincosf(wang * (float)(c * 64 + lane), &sv, &cv);
        tw0[c] = make_float2(cv, sv);
    }
    #pragma unroll
    for (int c = 0; c < 2; ++c) {
        float sv, cv; __sincosf(wang * (float)(2 * (c * 64 + lane)), &sv, &cv);
        tw1[c] = make_float2(cv, sv);
    }
    { float sv, cv; __sincosf(wang * (float)(4 * lane),          &sv, &cv); tw2 = make_float2(cv, sv); }
    { float sv, cv; __sincosf(wang * (float)(8 * (lane & 31)),   &sv, &cv); tw3 = make_float2(cv, sv); }
    { float sv, cv; __sincosf(wang * (float)(16 * (lane & 15)),  &sv, &cv); tw4 = make_float2(cv, sv); }
    { float sv, cv; __sincosf(wang * (float)(32 * (lane & 7)),   &sv, &cv); tw5 = make_float2(cv, sv); }
    { float sv, cv; __sincosf(wang * (float)(64 * (lane & 3)),   &sv, &cv); tw6 = make_float2(cv, sv); }
    { float sv, cv; __sincosf(wang * (float)(128 * (lane & 1)),  &sv, &cv); tw7 = make_float2(cv, sv); }

    // conjugate-partner lane index for register 0 (positions 0..63 in bit-rev domain)
    int jp0 = 0;
    if (lane >= 1) { const int msb = 31 - __builtin_clz((unsigned)lane); jp0 = lane ^ ((1 << msb) - 1); }

    float2 z[DEG][8];   // this wave's 3 sketches, position n = it*64 + lane

    // ---- pair loop: stage X -> cooperative gather -> handoff to owner wave ----
    for (int p = 0; p < 4; ++p) {
        const int pr0 = blockIdx.x * 8 + p * 2;
        const float4* X0q = (const float4*)(X + (size_t)pr0 * F_DIM);
        const float4* X1q = (const float4*)(X + (size_t)(pr0 + 1) * F_DIM);
        #pragma unroll
        for (int k = 0; k < 4; ++k) {
            const int i4 = tid + k * THREADS;
            const float4 a = X0q[i4];
            const float4 b = X1q[i4];
            xst4[2 * i4]     = make_float4(a.x, b.x, a.y, b.y);
            xst4[2 * i4 + 1] = make_float4(a.z, b.z, a.w, b.w);
        }
        __syncthreads();

        #pragma unroll
        for (int d = 0; d < DEG; ++d)
            #pragma unroll
            for (int h = 0; h < 2; ++h) {
                const int b = tid + (h << 8);
                const ushort* ep = ent_g + d * F_DIM;
                float ax = 0.0f, ay = 0.0f;
                int e = je0[d][h];
                const int eend = je1[d][h];
                // sign: bit=1 -> +1, bit=0 -> -1 (sgn = 2*bit - 1)
                for (; e + 4 <= eend; e += 4) {
                    const ushort u0 = ep[e], u1 = ep[e + 1], u2 = ep[e + 2], u3 = ep[e + 3];
                    const float2 v0 = xst[u0 & 4095], v1 = xst[u1 & 4095];
                    const float2 v2 = xst[u2 & 4095], v3 = xst[u3 & 4095];
                    const float s0 = (u0 & 0x8000) ? 1.0f : -1.0f;
                    const float s1 = (u1 & 0x8000) ? 1.0f : -1.0f;
                    const float s2 = (u2 & 0x8000) ? 1.0f : -1.0f;
                    const float s3 = (u3 & 0x8000) ? 1.0f : -1.0f;
                    ax += s0 * v0.x + s1 * v1.x + s2 * v2.x + s3 * v3.x;
                    ay += s0 * v0.y + s1 * v1.y + s2 * v2.y + s3 * v3.y;
                }
                for (; e < eend; ++e) {
                    const ushort u = ep[e];
                    const float2 v = xst[u & 4095];
                    const float s = (u & 0x8000) ? 1.0f : -1.0f;
                    ax += s * v.x; ay += s * v.y;
                }
                exch[d][b] = make_float2(ax, ay);   // stride-1, conflict-free
            }
        __syncthreads();

        if (wave == p) {
            #pragma unroll
            for (int d = 0; d < DEG; ++d)
                #pragma unroll
                for (int it = 0; it < 8; ++it)
                    z[d][it] = exch[d][it * 64 + lane];
        }
        __syncthreads();   // handoff read done before next pair overwrites
    }

    // ---- per degree: forward DIF FFT (regs+shuffles) + extraction + product ----
    float2 P0[8], P1[8];
    #pragma unroll
    for (int it = 0; it < 8; ++it) { P0[it] = make_float2(1.0f, 0.0f); P1[it] = make_float2(1.0f, 0.0f); }

    #pragma unroll
    for (int d = 0; d < DEG; ++d) {
        float2 s[8];
        #pragma unroll
        for (int it = 0; it < 8; ++it) s[it] = z[d][it];

        // stage 0 (h=256): pairs (c, c+4), w = tw0[c]
        #pragma unroll
        for (int c = 0; c < 4; ++c) {
            const float2 a = s[c], b = s[c + 4];
            s[c]     = make_float2(a.x + b.x, a.y + b.y);
            s[c + 4] = cmul(make_float2(a.x - b.x, a.y - b.y), tw0[c]);
        }
        // stage 1 (h=128): pairs (g*4+c, +2), w = tw1[c]
        #pragma unroll
        for (int g = 0; g < 2; ++g)
            #pragma unroll
            for (int c = 0; c < 2; ++c) {
                const int i1 = g * 4 + c, i2 = i1 + 2;
                const float2 a = s[i1], b = s[i2];
                s[i1] = make_float2(a.x + b.x, a.y + b.y);
                s[i2] = cmul(make_float2(a.x - b.x, a.y - b.y), tw1[c]);
            }
        // stage 2 (h=64): pairs (2g, 2g+1), w = tw2
        #pragma unroll
        for (int g = 0; g < 4; ++g) {
            const int i1 = 2 * g, i2 = i1 + 1;
            const float2 a = s[i1], b = s[i2];
            s[i1] = make_float2(a.x + b.x, a.y + b.y);
            s[i2] = cmul(make_float2(a.x - b.x, a.y - b.y), tw2);
        }
        // lane stages (h = 32..1)
        fwd_lane_stage(s, lane, 32, tw3);
        fwd_lane_stage(s, lane, 16, tw4);
        fwd_lane_stage(s, lane, 8,  tw5);
        fwd_lane_stage(s, lane, 4,  tw6);
        fwd_lane_stage(s, lane, 2,  tw7);
        fwd_lane_stage(s, lane, 1,  make_float2(1.0f, 0.0f));

        // extraction partners in bit-rev domain: jp = u ^ (2^msb(u)-1)
        float2 zp[8];
        zp[0] = make_float2(__shfl(s[0].x, jp0), __shfl(s[0].y, jp0));
        zp[1] = shflx(s[1], 63);
        zp[2] = shflx(s[3], 63);
        zp[3] = shflx(s[2], 63);
        zp[4] = shflx(s[7], 63);
        zp[5] = shflx(s[6], 63);
        zp[6] = shflx(s[5], 63);
        zp[7] = shflx(s[4], 63);
        #pragma unroll
        for (int it = 0; it < 8; ++it) {
            const float2 zk = s[it], zq = zp[it];
            const float2 A = make_float2(0.5f * (zk.x + zq.x), 0.5f * (zk.y - zq.y));
            const float2 B = make_float2(0.5f * (zk.y + zq.y), 0.5f * (zq.x - zk.x));
            P0[it] = cmul(P0[it], A);
            P1[it] = cmul(P1[it], B);
        }
    }

    // ---- Q = P0 + i*P1 (bit-rev order), inverse DIT in registers ----
    float2 q[8];
    #pragma unroll
    for (int it = 0; it < 8; ++it)
        q[it] = make_float2(P0[it].x - P1[it].y, P0[it].y + P1[it].x);

    inv_lane_stage(q, lane, 1,  make_float2(1.0f, 0.0f));
    inv_lane_stage(q, lane, 2,  tw7);
    inv_lane_stage(q, lane, 4,  tw6);
    inv_lane_stage(q, lane, 8,  tw5);
    inv_lane_stage(q, lane, 16, tw4);
    inv_lane_stage(q, lane, 32, tw3);
    // stage s=6: pairs (2g, 2g+1), w = conj(tw2)
    #pragma unroll
    for (int g = 0; g < 4; ++g) {
        const int i1 = 2 * g, i2 = i1 + 1;
        const float2 a = q[i1];
        const float2 t = cmulc(q[i2], tw2);
        q[i1] = make_float2(a.x + t.x, a.y + t.y);
        q[i2] = make_float2(a.x - t.x, a.y - t.y);
    }
    // stage s=7: pairs (g*4+c, +2), w = conj(tw1[c])
    #pragma unroll
    for (int g = 0; g < 2; ++g)
        #pragma unroll
        for (int c = 0; c < 2; ++c) {
            const int i1 = g * 4 + c, i2 = i1 + 2;
            const float2 a = q[i1];
            const float2 t = cmulc(q[i2], tw1[c]);
            q[i1] = make_float2(a.x + t.x, a.y + t.y);
            q[i2] = make_float2(a.x - t.x, a.y - t.y);
        }
    // stage s=8: pairs (c, c+4), w = conj(tw0[c])
    #pragma unroll
    for (int c = 0; c < 4; ++c) {
        const float2 a = q[c];
        const float2 t = cmulc(q[c + 4], tw0[c]);
        q[c]     = make_float2(a.x + t.x, a.y + t.y);
        q[c + 4] = make_float2(a.x - t.x, a.y - t.y);
    }

    // ---- store: natural order, Re -> row r0, Im -> row r0+1, scale 1/512 ----
    const float scale = 1.0f / (float)NC;
    const int r0 = blockIdx.x * 8 + wave * 2;
    float* o0 = out + (size_t)r0 * NC;
    float* o1 = o0 + NC;
    #pragma unroll
    for (int it = 0; it < 8; ++it) {
        const int n = it * 64 + lane;
        o0[n] = q[it].x * scale;
        o1[n] = q[it].y * scale;
    }
}

extern "C" void kernel_launch(void* const* d_in, const int* in_sizes, int n_in,
                              void* d_out, int out_size, void* d_ws, size_t ws_size,
                              hipStream_t stream) {
    const float* X    = (const float*)d_in[0];
    const int*   idxh = (const int*)d_in[1];
    const int*   bith = (const int*)d_in[2];
    float*       outp = (float*)d_out;

    ushort* ofs_g = (ushort*)d_ws;                              // 3*520*2 B < 4 KB
    ushort* ent_g = (ushort*)((char*)d_ws + ENT_BYTE_OFF);      // 3*4096*2 B = 24 KB

    build_csr<<<DEG, 512, 0, stream>>>(idxh, bith, ofs_g, ent_g);

    const int n_rows = in_sizes[0] / F_DIM;            // 8192
    const int blocks = n_rows / 8;                     // 1024 (4 pairs per block)
    ts_kernel<<<blocks, THREADS, 0, stream>>>(X, ofs_g, ent_g, outp);
}